// Round 3
// baseline (1399.997 us; speedup 1.0000x reference)
//
#include <hip/hip_runtime.h>
#include <hip/hip_bf16.h>

// Problem constants: B=4, LK=512, LQ=128, D=256, H=256, L=3
// d_in order: 0 keys[4,512,256] 1 queries[4,128,256] 2 W_k[256,256] 3 W_q[256,256]
//             4 w_v[1,256] 5 W_g_w[256,256] 6 W_g_b[256] 7 gru_Wih[3,768,256]
//             8 gru_Whh[3,768,256] 9 gru_bih[3,768] 10 gru_bhh[3,768]
// out: x [4,128,256] as float32 (reference output dtype)

typedef __attribute__((ext_vector_type(8))) short short8;
typedef __attribute__((ext_vector_type(4))) float f32x4;

__device__ __forceinline__ float fast_rcp(float x) { return __builtin_amdgcn_rcpf(x); }
__device__ __forceinline__ float fast_tanh(float x) {
    float e = __expf(2.f * x);
    return 1.f - 2.f * fast_rcp(1.f + e);
}
__device__ __forceinline__ float fast_sigmoid(float x) {
    return fast_rcp(1.f + __expf(-x));
}
__device__ __forceinline__ unsigned short f2bf(float v) {
    unsigned int b = __builtin_bit_cast(unsigned int, v);
    unsigned int r = (b + 0x7fffu + ((b >> 16) & 1u)) >> 16;
    return (unsigned short)r;
}

// out[row, n] = sum_k in[row, k] * W[n, k] (+ bias[n]); K fixed at 256.
__global__ void gemm_rowwise(const float* __restrict__ in, const float* __restrict__ W,
                             const float* __restrict__ bias, float* __restrict__ out, int N) {
    __shared__ float xrow[256];
    const int tid = threadIdx.x;
    const int row = blockIdx.x;
    xrow[tid] = in[row * 256 + tid];
    __syncthreads();
    const float4* xv = (const float4*)xrow;
    for (int n = tid; n < N; n += 256) {
        const float4* wv = (const float4*)(W + n * 256);
        float s = 0.f;
#pragma unroll 8
        for (int k4 = 0; k4 < 64; ++k4) {
            float4 a = xv[k4];
            float4 b = wv[k4];
            s += a.x * b.x + a.y * b.y + a.z * b.z + a.w * b.w;
        }
        if (bias) s += bias[n];
        out[row * N + n] = s;
    }
}

// e[b,q,k] = exp( sum_h w_v[h]*tanh(Qp[b,q,h]+Kp[b,k,h]) ); denom[q] += sum over (b,k)
__global__ void attn_scores(const float* __restrict__ Kp, const float* __restrict__ Qp,
                            const float* __restrict__ wv, float* __restrict__ e,
                            float* __restrict__ denom) {
    __shared__ float qrow[256];
    __shared__ float wvr[256];
    __shared__ float wsum[4];
    const int tid = threadIdx.x;
    const int row = blockIdx.x;      // b*128 + q
    const int b = row >> 7, q = row & 127;
    qrow[tid] = Qp[row * 256 + tid];
    wvr[tid] = wv[tid];
    __syncthreads();
    const int lane = tid & 63, w = tid >> 6;
    const float4 qv = ((const float4*)qrow)[lane];
    const float4 wvv = ((const float4*)wvr)[lane];
    float dsum = 0.f;
    for (int k = w; k < 512; k += 4) {
        const float4 kv = *(const float4*)(Kp + (b * 512 + k) * 256 + lane * 4);
        float s = fast_tanh(qv.x + kv.x) * wvv.x;
        s += fast_tanh(qv.y + kv.y) * wvv.y;
        s += fast_tanh(qv.z + kv.z) * wvv.z;
        s += fast_tanh(qv.w + kv.w) * wvv.w;
#pragma unroll
        for (int m = 1; m < 64; m <<= 1) s += __shfl_xor(s, m);
        if (lane == 0) {
            float ev = __expf(s);
            e[row * 512 + k] = ev;
            dsum += ev;
        }
    }
    if (lane == 0) wsum[w] = dsum;
    __syncthreads();
    if (tid == 0) atomicAdd(&denom[q], wsum[0] + wsum[1] + wsum[2] + wsum[3]);
}

// rep + gate + x0
__global__ void rep_gate(const float* __restrict__ e, const float* __restrict__ denom,
                         const float* __restrict__ keys, const float* __restrict__ queries,
                         const float* __restrict__ Wg, const float* __restrict__ bg,
                         float* __restrict__ x0) {
    __shared__ float att[512];
    __shared__ float urow[256];
    const int tid = threadIdx.x;
    const int row = blockIdx.x;      // b*128 + q
    const int b = row >> 7, q = row & 127;
    const float inv = 1.f / denom[q];
    att[tid] = e[row * 512 + tid] * inv;
    att[tid + 256] = e[row * 512 + 256 + tid] * inv;
    __syncthreads();
    float racc = 0.f;
#pragma unroll 4
    for (int k = 0; k < 512; ++k) racc += att[k] * keys[(b * 512 + k) * 256 + tid];
    const float u = queries[row * 256 + tid] + racc;
    urow[tid] = u;
    __syncthreads();
    const float4* uv = (const float4*)urow;
    const float4* wr = (const float4*)(Wg + tid * 256);
    float g = 0.f;
#pragma unroll 8
    for (int k4 = 0; k4 < 64; ++k4) {
        float4 a = uv[k4];
        float4 wq = wr[k4];
        g += a.x * wq.x + a.y * wq.y + a.z * wq.z + a.w * wq.w;
    }
    g += bg[tid];
    x0[row * 256 + tid] = fast_sigmoid(g) * u;
}

__global__ void copy_out(const float* __restrict__ in, float* __restrict__ out, int n) {
    int i = blockIdx.x * blockDim.x + threadIdx.x;
    if (i < n) out[i] = in[i];
}

// Sequential GRU layer: 1 workgroup, 8 waves. Whh converted f32->bf16 in-register
// and held in VGPRs as MFMA B-fragments. Per step: gh = h@Whh^T via
// 48 MFMA(16x16x32)/wave (M=4 padded to 16).
__launch_bounds__(512, 2)
__global__ void gru_seq(const float* __restrict__ gi,          // [512][768] (includes bih)
                        const float* __restrict__ whh,          // [768][256] f32 row-major
                        const float* __restrict__ bhh,          // [768]
                        float* __restrict__ xout) {             // [512][256]
    // abuf[ks][hi][row][j]: bf16 A-fragment staging; element (row=batch, k=ks*32+hi*8+j)
    __shared__ __align__(16) unsigned short abuf[8][4][16][8];  // 8KB
    __shared__ float gibuf[2][3072];                            // 24KB (gi row double-buffer)
    __shared__ float hsm[4][256];                               // 4KB  (h state, f32)

    const int tid = threadIdx.x;
    const int lane = tid & 63, w = tid >> 6;
    const int l15 = lane & 15, lhi = lane >> 4;

    // zero abuf (rows 4..15 stay zero forever -> padded M) and h
    for (int i = tid; i < 4096; i += 512) ((unsigned short*)abuf)[i] = 0;
    for (int i = tid; i < 1024; i += 512) ((float*)hsm)[i] = 0.f;

    // B-fragment preload (f32 -> bf16): wave w owns tiles {2w,2w+1, 16+2w,16+2w+1, 32+2w,32+2w+1}
    short8 bf[6][8];
    {
        const int t0 = 2 * w, t1 = 2 * w + 1;
        const int tiles[6] = {t0, t1, 16 + t0, 16 + t1, 32 + t0, 32 + t1};
#pragma unroll
        for (int i = 0; i < 6; ++i) {
            const float* basef = whh + (tiles[i] * 16 + l15) * 256 + lhi * 8;
#pragma unroll
            for (int ks = 0; ks < 8; ++ks) {
                const float4 a0 = *(const float4*)(basef + ks * 32);
                const float4 a1 = *(const float4*)(basef + ks * 32 + 4);
                short8 v;
                v[0] = (short)f2bf(a0.x); v[1] = (short)f2bf(a0.y);
                v[2] = (short)f2bf(a0.z); v[3] = (short)f2bf(a0.w);
                v[4] = (short)f2bf(a1.x); v[5] = (short)f2bf(a1.y);
                v[6] = (short)f2bf(a1.z); v[7] = (short)f2bf(a1.w);
                bf[i][ks] = v;
            }
        }
    }
    // bias preload (valid for lanes 0-15)
    float bh0[2], bh1[2], bh2[2];
#pragma unroll
    for (int p = 0; p < 2; ++p) {
        const int hc = 32 * w + 16 * p + l15;
        bh0[p] = bhh[hc];
        bh1[p] = bhh[256 + hc];
        bh2[p] = bhh[512 + hc];
    }
    // preload gi row 0 into gibuf[0]
    {
#pragma unroll
        for (int m = 0; m < 6; ++m) {
            const int j = tid + 512 * m;
            const int b = j / 768, c = j - b * 768;
            gibuf[0][j] = gi[b * 98304 + c];
        }
    }
    __syncthreads();

    for (int t = 0; t < 128; ++t) {
        // issue gi prefetch for t+1 (global loads; no dependence on h)
        float gtmp[6];
        if (t < 127) {
#pragma unroll
            for (int m = 0; m < 6; ++m) {
                const int j = tid + 512 * m;
                const int b = j / 768, c = j - b * 768;
                gtmp[m] = gi[b * 98304 + (t + 1) * 768 + c];
            }
        }
        // MFMA: gh = h~ @ Whh^T
        f32x4 acc[6];
#pragma unroll
        for (int i = 0; i < 6; ++i)
#pragma unroll
            for (int c = 0; c < 4; ++c) acc[i][c] = 0.f;
#pragma unroll
        for (int ks = 0; ks < 8; ++ks) {
            const short8 a = *(const short8*)&abuf[ks][lhi][l15][0];
#pragma unroll
            for (int i = 0; i < 6; ++i)
                acc[i] = __builtin_amdgcn_mfma_f32_16x16x32_bf16(a, bf[i][ks], acc[i], 0, 0, 0);
        }
        // store gi prefetch to LDS
        if (t < 127) {
#pragma unroll
            for (int m = 0; m < 6; ++m) gibuf[(t + 1) & 1][tid + 512 * m] = gtmp[m];
        }
        __syncthreads();   // all abuf reads done; gibuf[t+1] visible after next barrier

        // epilogue: lanes 0-15 own (batch=reg, col=l15) of each tile
        if (lane < 16) {
            const float* gcur = gibuf[t & 1];
#pragma unroll
            for (int p = 0; p < 2; ++p) {
                const int hc = 32 * w + 16 * p + l15;
#pragma unroll
                for (int b = 0; b < 4; ++b) {
                    const float ghr = acc[0 + p][b] + bh0[p];
                    const float ghz = acc[2 + p][b] + bh1[p];
                    const float ghn = acc[4 + p][b] + bh2[p];
                    const float gir = gcur[b * 768 + hc];
                    const float giz = gcur[b * 768 + 256 + hc];
                    const float gin = gcur[b * 768 + 512 + hc];
                    const float r = fast_sigmoid(gir + ghr);
                    const float z = fast_sigmoid(giz + ghz);
                    const float nn = fast_tanh(gin + r * ghn);
                    const float ho = hsm[b][hc];
                    const float hn = nn + z * (ho - nn);
                    hsm[b][hc] = hn;
                    xout[(b * 128 + t) * 256 + hc] = hn;
                    abuf[hc >> 5][(hc >> 3) & 3][b][hc & 7] = f2bf(hn);
                }
            }
        }
        __syncthreads();   // abuf/h/gibuf ready for next step
    }
}

extern "C" void kernel_launch(void* const* d_in, const int* in_sizes, int n_in,
                              void* d_out, int out_size, void* d_ws, size_t ws_size,
                              hipStream_t stream) {
    (void)in_sizes; (void)n_in; (void)out_size; (void)ws_size;
    const float* keys    = (const float*)d_in[0];
    const float* queries = (const float*)d_in[1];
    const float* W_k     = (const float*)d_in[2];
    const float* W_q     = (const float*)d_in[3];
    const float* w_v     = (const float*)d_in[4];
    const float* W_g_w   = (const float*)d_in[5];
    const float* W_g_b   = (const float*)d_in[6];
    const float* Wih     = (const float*)d_in[7];
    const float* Whh     = (const float*)d_in[8];
    const float* bih     = (const float*)d_in[9];
    const float* bhh     = (const float*)d_in[10];

    float* ws = (float*)d_ws;
    float* Kp_gi = ws;             // 524288 (Kp; reused as gi after attention phase)
    float* Qp   = ws + 524288;     // 131072
    float* e    = ws + 655360;     // 262144
    float* den  = ws + 917504;     // 256 (128 used)
    float* xA   = ws + 917760;     // 131072
    float* xB   = ws + 1048832;    // 131072
    // total: 1179904 floats = 4.5 MB

    hipMemsetAsync((void*)den, 0, 512, stream);

    gemm_rowwise<<<2048, 256, 0, stream>>>(keys, W_k, nullptr, Kp_gi, 256);
    gemm_rowwise<<<512, 256, 0, stream>>>(queries, W_q, nullptr, Qp, 256);
    attn_scores<<<512, 256, 0, stream>>>(Kp_gi, Qp, w_v, e, den);
    rep_gate<<<512, 256, 0, stream>>>(e, den, keys, queries, W_g_w, W_g_b, xA);

    float* gi  = Kp_gi;   // Kp dead after attn_scores
    float* xin = xA;
    float* xo  = xB;
    for (int l = 0; l < 3; ++l) {
        gemm_rowwise<<<512, 256, 0, stream>>>(xin, Wih + l * 196608, bih + l * 768, gi, 768);
        gru_seq<<<1, 512, 0, stream>>>(gi, Whh + l * 196608, bhh + l * 768, xo);
        float* tmp = xin; xin = xo; xo = tmp;
    }
    copy_out<<<512, 256, 0, stream>>>(xin, (float*)d_out, 131072);
}